// Round 5
// baseline (527.877 us; speedup 1.0000x reference)
//
#include <hip/hip_runtime.h>

typedef __bf16 bf16;
typedef __attribute__((ext_vector_type(8))) __bf16 bf16x8;
typedef __attribute__((ext_vector_type(4))) float f32x4;
typedef unsigned short u16;

#define LSTR  40   // LDS row stride (bf16) for 32-wide K tiles -> 2-way bank alias (free)
#define LSTR2 72   // LDS row stride (bf16) for 64-wide tiles, 16B-aligned rows, 2-way alias
#define BN_EPS 1e-5f

// ---------------- prep: transpose fp32 weights -> bf16 transposed in ws; zero cnt -------
__global__ __launch_bounds__(256) void k_prep(
        const float* __restrict__ W0, const float* __restrict__ W1, const float* __restrict__ W2,
        bf16* __restrict__ Wt0, bf16* __restrict__ Wt1, bf16* __restrict__ Wt2,
        int* __restrict__ cnt, int n)
{
    int i = blockIdx.x*256 + threadIdx.x;
    const int T = 768*64 + 8192;
    if (i < 768*64)            { int k = i>>6, n_ = i&63;                  Wt0[n_*768+k] = (bf16)W0[i]; }
    else if (i < 768*64+4096)  { int j = i-768*64;      int k=j>>6,c=j&63; Wt1[c*64+k]  = (bf16)W1[j]; }
    else if (i < T)            { int j = i-768*64-4096; int k=j>>6,c=j&63; Wt2[c*64+k]  = (bf16)W2[j]; }
    int j = i - T;
    if (j >= 0 && j < n) cnt[j] = 0;      // self-loops handled inline in gat_agg
}

// ---------------- FUSED proj GEMM (K=768) + BN/ELU + layer-1 GEMM (K=64) + logits -------
// (R2-proven version: 1-deep register prefetch, LDS double buffer)
__global__ __launch_bounds__(256) void k_fused_proj(
        const float* __restrict__ A, const bf16* __restrict__ Bt,   // x, Wt0[64][768]
        const bf16* __restrict__ W1t, int M,                        // Wt1[64][64] (n,k)
        const float* __restrict__ pb, const float* __restrict__ g,
        const float* __restrict__ bb, const float* __restrict__ mm, const float* __restrict__ vv,
        const float* __restrict__ att_s, const float* __restrict__ att_d,
        bf16* __restrict__ h0b, bf16* __restrict__ xwb,
        float* __restrict__ a_s, float* __restrict__ a_d)
{
    const int K = 768;
    __shared__ bf16 xs[2][64*LSTR];
    __shared__ bf16 bs[2][64*LSTR];
    __shared__ bf16 hs [64*LSTR2];
    __shared__ bf16 w1s[64*LSTR2];
    __shared__ float sC[64], cC[64];

    int t = threadIdx.x;
    int w = t >> 6, lane = t & 63;
    int q = lane >> 4, l16 = lane & 15;
    int row0 = blockIdx.x * 64;
    int sRow = t >> 2, sK = (t & 3) * 8;

    if (t < 64) {
        float s = rsqrtf(vv[t] + BN_EPS) * g[t];
        sC[t] = s;
        cC[t] = (pb[t] - mm[t]) * s + bb[t];
    }
    {
        int r = t >> 2, c0 = (t & 3) * 16;
        *(bf16x8*)(w1s + r*LSTR2 + c0)     = *(const bf16x8*)(W1t + r*64 + c0);
        *(bf16x8*)(w1s + r*LSTR2 + c0 + 8) = *(const bf16x8*)(W1t + r*64 + c0 + 8);
    }

    auto loadA = [&](int k0) -> bf16x8 {
        bf16x8 xv;
        #pragma unroll
        for (int i = 0; i < 8; ++i) xv[i] = (bf16)0.f;
        int gr = row0 + sRow;
        if (gr < M) {
            const float* ap = A + (size_t)gr*K + k0 + sK;
            float4 f0 = *(const float4*)ap;
            float4 f1 = *(const float4*)(ap + 4);
            xv[0]=(bf16)f0.x; xv[1]=(bf16)f0.y; xv[2]=(bf16)f0.z; xv[3]=(bf16)f0.w;
            xv[4]=(bf16)f1.x; xv[5]=(bf16)f1.y; xv[6]=(bf16)f1.z; xv[7]=(bf16)f1.w;
        }
        return xv;
    };
    auto loadB = [&](int k0) -> bf16x8 {
        return *(const bf16x8*)(Bt + (size_t)sRow*K + k0 + sK);
    };

    f32x4 acc[4];
    #pragma unroll
    for (int i = 0; i < 4; ++i) { acc[i][0]=0.f; acc[i][1]=0.f; acc[i][2]=0.f; acc[i][3]=0.f; }

    bf16x8 xv = loadA(0);
    bf16x8 bv = loadB(0);
    *(bf16x8*)(&xs[0][sRow*LSTR + sK]) = xv;
    *(bf16x8*)(&bs[0][sRow*LSTR + sK]) = bv;
    __syncthreads();

    int cur = 0;
    for (int k0 = 0; k0 < K; k0 += 32) {
        if (k0 + 32 < K) {                // prefetch next tile into registers
            xv = loadA(k0 + 32);
            bv = loadB(k0 + 32);
        }
        bf16x8 af = *(bf16x8*)(&xs[cur][(w*16 + l16)*LSTR + q*8]);
        #pragma unroll
        for (int tt = 0; tt < 4; ++tt) {
            bf16x8 bfr = *(bf16x8*)(&bs[cur][(tt*16 + l16)*LSTR + q*8]);
            acc[tt] = __builtin_amdgcn_mfma_f32_16x16x32_bf16(af, bfr, acc[tt], 0, 0, 0);
        }
        if (k0 + 32 < K) {                // write next tile to alternate buffer: 1 barrier/iter
            *(bf16x8*)(&xs[cur^1][sRow*LSTR + sK]) = xv;
            *(bf16x8*)(&bs[cur^1][sRow*LSTR + sK]) = bv;
            __syncthreads();
            cur ^= 1;
        }
    }

    // epilogue 1: h0 = ELU(BN(acc)) -> global h0b + LDS hs
    #pragma unroll
    for (int tt = 0; tt < 4; ++tt) {
        int col = tt*16 + l16;
        #pragma unroll
        for (int r = 0; r < 4; ++r) {
            int rl = w*16 + q*4 + r;
            float val = acc[tt][r] * sC[col] + cC[col];
            val = val > 0.f ? val : __expf(val) - 1.f;   // ELU
            hs[rl*LSTR2 + col] = (bf16)val;
            int row = row0 + rl;
            if (row < M) h0b[(size_t)row*64 + col] = (bf16)val;
        }
    }
    __syncthreads();

    // second GEMM: xw1 = h0_tile(64x64) @ W1 (K=64, 2 K-steps)
    f32x4 acc2[4];
    #pragma unroll
    for (int i = 0; i < 4; ++i) { acc2[i][0]=0.f; acc2[i][1]=0.f; acc2[i][2]=0.f; acc2[i][3]=0.f; }
    #pragma unroll
    for (int ks = 0; ks < 2; ++ks) {
        bf16x8 af = *(bf16x8*)(&hs[(w*16 + l16)*LSTR2 + ks*32 + q*8]);
        #pragma unroll
        for (int tt = 0; tt < 4; ++tt) {
            bf16x8 bfr = *(bf16x8*)(&w1s[(tt*16 + l16)*LSTR2 + ks*32 + q*8]);
            acc2[tt] = __builtin_amdgcn_mfma_f32_16x16x32_bf16(af, bfr, acc2[tt], 0, 0, 0);
        }
    }

    // epilogue 2: xwb (bf16) + fused H=8 attention logits from fp32 accumulator
    #pragma unroll
    for (int tt = 0; tt < 4; ++tt) {
        int col = tt*16 + l16;
        #pragma unroll
        for (int r = 0; r < 4; ++r) {
            int row = row0 + w*16 + q*4 + r;
            if (row < M) xwb[(size_t)row*64 + col] = (bf16)acc2[tt][r];
        }
    }
    #pragma unroll
    for (int r = 0; r < 4; ++r) {
        int row = row0 + w*16 + q*4 + r;
        float ps[4], pd[4];
        #pragma unroll
        for (int tt = 0; tt < 4; ++tt) {
            int col = tt*16 + l16;          // head = col>>3 = 2*tt + (l16>>3)
            ps[tt] = acc2[tt][r] * att_s[col];
            pd[tt] = acc2[tt][r] * att_d[col];
        }
        #pragma unroll
        for (int off = 1; off < 8; off <<= 1) {
            #pragma unroll
            for (int tt = 0; tt < 4; ++tt) {
                ps[tt] += __shfl_xor(ps[tt], off);
                pd[tt] += __shfl_xor(pd[tt], off);
            }
        }
        if ((l16 & 7) == 0 && row < M) {
            int hb = l16 >> 3;
            #pragma unroll
            for (int tt = 0; tt < 4; ++tt) {
                a_s[row*8 + 2*tt + hb] = ps[tt];
                a_d[row*8 + 2*tt + hb] = pd[tt];
            }
        }
    }
}

// ---------------- MFMA GEMM for layer 2 (K=64): raw xw + fused H=1 logits ---------------
template<int MODE, bool ABF, int H>
__global__ __launch_bounds__(256) void k_gemm64(
        const void* __restrict__ Av, const bf16* __restrict__ Bt, int M, int K,
        const float* __restrict__ pb, const float* __restrict__ g, const float* __restrict__ bb,
        const float* __restrict__ mm, const float* __restrict__ vv,
        bf16* __restrict__ outB,
        float* __restrict__ a_s, float* __restrict__ a_d,
        const float* __restrict__ att_s, const float* __restrict__ att_d)
{
    __shared__ bf16 xs[64*LSTR];
    __shared__ bf16 bs[64*LSTR];
    __shared__ float sC[64], cC[64];

    int t = threadIdx.x;
    int w = t >> 6, lane = t & 63;
    int q = lane >> 4, l16 = lane & 15;
    int row0 = blockIdx.x * 64;
    int sRow = t >> 2, sK = (t & 3) * 8;

    auto loadA = [&](int k0) -> bf16x8 {
        bf16x8 xv;
        #pragma unroll
        for (int i = 0; i < 8; ++i) xv[i] = (bf16)0.f;
        int gr = row0 + sRow;
        if (gr < M) {
            if constexpr (ABF) {
                xv = *(const bf16x8*)((const bf16*)Av + (size_t)gr*K + k0 + sK);
            } else {
                const float* ap = (const float*)Av + (size_t)gr*K + k0 + sK;
                float4 f0 = *(const float4*)ap;
                float4 f1 = *(const float4*)(ap + 4);
                xv[0]=(bf16)f0.x; xv[1]=(bf16)f0.y; xv[2]=(bf16)f0.z; xv[3]=(bf16)f0.w;
                xv[4]=(bf16)f1.x; xv[5]=(bf16)f1.y; xv[6]=(bf16)f1.z; xv[7]=(bf16)f1.w;
            }
        }
        return xv;
    };
    auto loadB = [&](int k0) -> bf16x8 {
        return *(const bf16x8*)(Bt + (size_t)sRow*K + k0 + sK);
    };

    f32x4 acc[4];
    #pragma unroll
    for (int i = 0; i < 4; ++i) { acc[i][0]=0.f; acc[i][1]=0.f; acc[i][2]=0.f; acc[i][3]=0.f; }

    bf16x8 xv = loadA(0);
    bf16x8 bv = loadB(0);

    for (int k0 = 0; k0 < K; k0 += 32) {
        *(bf16x8*)(xs + sRow*LSTR + sK) = xv;
        *(bf16x8*)(bs + sRow*LSTR + sK) = bv;
        __syncthreads();
        if (k0 + 32 < K) {
            xv = loadA(k0 + 32);
            bv = loadB(k0 + 32);
        }
        bf16x8 af = *(bf16x8*)(xs + (w*16 + l16)*LSTR + q*8);
        #pragma unroll
        for (int tt = 0; tt < 4; ++tt) {
            bf16x8 bfr = *(bf16x8*)(bs + (tt*16 + l16)*LSTR + q*8);
            acc[tt] = __builtin_amdgcn_mfma_f32_16x16x32_bf16(af, bfr, acc[tt], 0, 0, 0);
        }
        __syncthreads();
    }

    if constexpr (MODE == 0) {
        if (t < 64) {
            float s = rsqrtf(vv[t] + BN_EPS) * g[t];
            sC[t] = s;
            cC[t] = (pb[t] - mm[t]) * s + bb[t];
        }
        __syncthreads();
    }

    #pragma unroll
    for (int tt = 0; tt < 4; ++tt) {
        int col = tt*16 + l16;
        #pragma unroll
        for (int r = 0; r < 4; ++r) {
            int row = row0 + w*16 + q*4 + r;
            if (row < M) {
                float val = acc[tt][r];
                if constexpr (MODE == 0) {
                    val = val * sC[col] + cC[col];
                    val = val > 0.f ? val : __expf(val) - 1.f;
                }
                outB[(size_t)row*64 + col] = (bf16)val;
            }
        }
    }

    if constexpr (MODE == 1) {
        #pragma unroll
        for (int r = 0; r < 4; ++r) {
            int row = row0 + w*16 + q*4 + r;
            if constexpr (H == 1) {
                float ps = 0.f, pd = 0.f;
                #pragma unroll
                for (int tt = 0; tt < 4; ++tt) {
                    int col = tt*16 + l16;
                    ps += acc[tt][r] * att_s[col];
                    pd += acc[tt][r] * att_d[col];
                }
                #pragma unroll
                for (int off = 1; off < 16; off <<= 1) {
                    ps += __shfl_xor(ps, off);
                    pd += __shfl_xor(pd, off);
                }
                if (l16 == 0 && row < M) { a_s[row] = ps; a_d[row] = pd; }
            } else {
                float ps[4], pd[4];
                #pragma unroll
                for (int tt = 0; tt < 4; ++tt) {
                    int col = tt*16 + l16;
                    ps[tt] = acc[tt][r] * att_s[col];
                    pd[tt] = acc[tt][r] * att_d[col];
                }
                #pragma unroll
                for (int off = 1; off < 8; off <<= 1) {
                    #pragma unroll
                    for (int tt = 0; tt < 4; ++tt) {
                        ps[tt] += __shfl_xor(ps[tt], off);
                        pd[tt] += __shfl_xor(pd[tt], off);
                    }
                }
                if ((l16 & 7) == 0 && row < M) {
                    int hb = l16 >> 3;
                    #pragma unroll
                    for (int tt = 0; tt < 4; ++tt) {
                        a_s[row*8 + 2*tt + hb] = ps[tt];
                        a_d[row*8 + 2*tt + hb] = pd[tt];
                    }
                }
            }
        }
    }
}

// ---------------- CSR build (edges only; self-loops inline in gat_agg) ----------------
__global__ __launch_bounds__(256) void k_count(const int* __restrict__ dst, int E, int* cnt) {
    int i = blockIdx.x*256 + threadIdx.x;
    if (i < E) atomicAdd(&cnt[dst[i]], 1);
}
__global__ __launch_bounds__(256) void k_scan_block(const int* __restrict__ cnt,
        int* __restrict__ rp, int* __restrict__ bsum, int n) {
    __shared__ int s[256];
    int t = threadIdx.x, v = blockIdx.x*256 + t;
    int x = (v < n) ? cnt[v] : 0;
    s[t] = x; __syncthreads();
    for (int off = 1; off < 256; off <<= 1) {
        int y = (t >= off) ? s[t-off] : 0;
        __syncthreads();
        s[t] += y;
        __syncthreads();
    }
    if (v < n) rp[v+1] = s[t];
    if (t == 255) bsum[blockIdx.x] = s[255];
}
// finalize with fused bsum scan (nb <= 256; N=50000 -> nb=196)
__global__ __launch_bounds__(256) void k_finalize(int* __restrict__ rp, const int* __restrict__ bsum,
        const int* __restrict__ cnt, int* __restrict__ cursor, int n, int nb) {
    __shared__ int s[256];
    int t = threadIdx.x;
    int x = (t < nb) ? bsum[t] : 0;
    s[t] = x; __syncthreads();
    for (int off = 1; off < 256; off <<= 1) {
        int y = (t >= off) ? s[t-off] : 0;
        __syncthreads();
        s[t] += y;
        __syncthreads();
    }
    int v = blockIdx.x*256 + t;
    if (v < n) {
        int b = v >> 8;
        int off0 = (b == 0) ? 0 : s[b-1];
        int val = rp[v+1] + off0;
        rp[v+1] = val;
        cursor[v] = val - cnt[v];          // = rp[v]
        if (v == 0) rp[0] = 0;
    }
}
__global__ __launch_bounds__(256) void k_scatter(const int* __restrict__ src, const int* __restrict__ dst,
        int E, int* __restrict__ cursor, u16* __restrict__ in_src) {
    int i = blockIdx.x*256 + threadIdx.x;
    if (i < E) {
        int pos = atomicAdd(&cursor[dst[i]], 1);
        in_src[pos] = (u16)src[i];         // N < 65536
    }
}

// ---------------- GAT aggregation, 8-edges-per-wave + index pipelining ------------------
// lane = eg*8 + s: edge-group eg (0..7) handles edge e+eg / e+8+eg; lane s owns channels
// 8s..8s+7 via one 16B bf16x8 load (full 128B row per edge in one gather slot).
// Indices for block k+1 are loaded during block k's compute (hides idx->gather chain).
// Merge: butterfly over eg bits {8,16,32}.
template<int H, bool CLS>
__global__ __launch_bounds__(256) void k_gat_agg(const bf16* __restrict__ xwb,
        const float* __restrict__ a_src, const float* __restrict__ a_dst,
        const int* __restrict__ rp, const u16* __restrict__ in_src,
        const float* __restrict__ bias,
        const float* __restrict__ g_, const float* __restrict__ bb,
        const float* __restrict__ mm, const float* __restrict__ vv,
        const bf16* __restrict__ resid, bf16* __restrict__ outB, float* __restrict__ outF,
        const float* __restrict__ clsW, const float* __restrict__ clsb, int n)
{
    int wv = (blockIdx.x*256 + threadIdx.x) >> 6;
    int lane = threadIdx.x & 63;
    if (wv >= n) return;
    int eg = lane >> 3;          // edge group 0..7
    int s  = lane & 7;           // channel octet
    int c0 = s * 8;
    int h  = (H == 8) ? s : 0;   // H=8: head = c>>3 = s
    float adst = a_dst[(size_t)wv*H + h];

    float acc[8];
    #pragma unroll
    for (int j = 0; j < 8; ++j) acc[j] = 0.f;
    float den = 0.f;

    if (eg == 0) {               // self-loop, once
        float asf = a_src[(size_t)wv*H + h] + adst;
        asf = (asf > 0.f) ? asf : 0.2f*asf;
        float ex = __expf(asf);
        bf16x8 xw = *(const bf16x8*)(xwb + (size_t)wv*64 + c0);
        #pragma unroll
        for (int j = 0; j < 8; ++j) acc[j] = ex * (float)xw[j];
        den = ex;
    }

    int beg = rp[wv], end = rp[wv+1];
    int e = beg;
    bool act0 = false, act1 = false;
    int u0 = 0, u1 = 0;
    if (e < end) {               // prefetch indices for block 0
        int i0 = e + eg, i1 = e + 8 + eg;
        act0 = i0 < end; act1 = i1 < end;
        u0 = act0 ? (int)in_src[i0] : 0;
        u1 = act1 ? (int)in_src[i1] : 0;
    }
    while (e < end) {
        // gathers for current 16-edge block (indices already resident)
        float s0 = a_src[(size_t)u0*H + h];
        float s1 = a_src[(size_t)u1*H + h];
        bf16x8 x0 = *(const bf16x8*)(xwb + (size_t)u0*64 + c0);
        bf16x8 x1 = *(const bf16x8*)(xwb + (size_t)u1*64 + c0);
        bool a0c = act0, a1c = act1;
        int en = e + 16;
        if (en < end) {          // prefetch next block's indices during compute
            int i0 = en + eg, i1 = en + 8 + eg;
            act0 = i0 < end; act1 = i1 < end;
            u0 = act0 ? (int)in_src[i0] : 0;
            u1 = act1 ? (int)in_src[i1] : 0;
        }
        float al0 = s0 + adst; al0 = (al0 > 0.f) ? al0 : 0.2f*al0;
        float al1 = s1 + adst; al1 = (al1 > 0.f) ? al1 : 0.2f*al1;
        float e0 = a0c ? __expf(al0) : 0.f;
        float e1 = a1c ? __expf(al1) : 0.f;
        #pragma unroll
        for (int j = 0; j < 8; ++j) acc[j] += e0*(float)x0[j] + e1*(float)x1[j];
        den += e0 + e1;
        e = en;
    }

    // merge the 8 edge-group partials (lane bits 8,16,32)
    #pragma unroll
    for (int off = 8; off < 64; off <<= 1) {
        #pragma unroll
        for (int j = 0; j < 8; ++j) acc[j] += __shfl_xor(acc[j], off);
        den += __shfl_xor(den, off);
    }

    float inv = 1.f / den;
    f32x4 bi0 = *(const f32x4*)(bias + c0), bi1 = *(const f32x4*)(bias + c0 + 4);
    f32x4 vv0 = *(const f32x4*)(vv + c0),   vv1 = *(const f32x4*)(vv + c0 + 4);
    f32x4 gg0 = *(const f32x4*)(g_ + c0),   gg1 = *(const f32x4*)(g_ + c0 + 4);
    f32x4 mm0 = *(const f32x4*)(mm + c0),   mm1 = *(const f32x4*)(mm + c0 + 4);
    f32x4 bb0 = *(const f32x4*)(bb + c0),   bb1 = *(const f32x4*)(bb + c0 + 4);
    bf16x8 rz = *(const bf16x8*)(resid + (size_t)wv*64 + c0);
    float v[8];
    #pragma unroll
    for (int j = 0; j < 8; ++j) {
        float bij = (j < 4) ? bi0[j] : bi1[j-4];
        float vvj = (j < 4) ? vv0[j] : vv1[j-4];
        float ggj = (j < 4) ? gg0[j] : gg1[j-4];
        float mmj = (j < 4) ? mm0[j] : mm1[j-4];
        float bbj = (j < 4) ? bb0[j] : bb1[j-4];
        float val = acc[j]*inv + bij;
        float sc = rsqrtf(vvj + BN_EPS) * ggj;
        val = (val - mmj) * sc + bbj;
        val += (float)rz[j];
        val = (val > 0.f) ? val : __expf(val) - 1.f;   // ELU
        v[j] = val;
    }

    if constexpr (!CLS) {
        if (eg == 0) {
            bf16x8 o;
            #pragma unroll
            for (int j = 0; j < 8; ++j) o[j] = (bf16)v[j];
            *(bf16x8*)(outB + (size_t)wv*64 + c0) = o;
        }
    } else {
        // classifier: v[] identical across eg groups; per-lane partial over its octet,
        // butterfly over s-bits {1,2,4} -> full dot replicated in every lane.
        float p[8];
        #pragma unroll
        for (int o = 0; o < 8; ++o) p[o] = 0.f;
        #pragma unroll
        for (int j = 0; j < 8; ++j) {
            f32x4 w0 = *(const f32x4*)(clsW + (c0+j)*8);
            f32x4 w1 = *(const f32x4*)(clsW + (c0+j)*8 + 4);
            p[0] += v[j]*w0[0]; p[1] += v[j]*w0[1]; p[2] += v[j]*w0[2]; p[3] += v[j]*w0[3];
            p[4] += v[j]*w1[0]; p[5] += v[j]*w1[1]; p[6] += v[j]*w1[2]; p[7] += v[j]*w1[3];
        }
        #pragma unroll
        for (int off = 1; off < 8; off <<= 1) {
            #pragma unroll
            for (int o = 0; o < 8; ++o) p[o] += __shfl_xor(p[o], off);
        }
        if (lane < 8) outF[(size_t)wv*8 + lane] = p[lane] + clsb[lane];
    }
}

// ---------------- host ----------------
extern "C" void kernel_launch(void* const* d_in, const int* in_sizes, int n_in,
                              void* d_out, int out_size, void* d_ws, size_t ws_size,
                              hipStream_t stream)
{
    const float* x      = (const float*)d_in[0];
    const int*   ei     = (const int*)  d_in[1];
    const float* proj_W = (const float*)d_in[2];
    const float* proj_b = (const float*)d_in[3];
    const float* bn1_g  = (const float*)d_in[4];
    const float* bn1_b  = (const float*)d_in[5];
    const float* bn1_m  = (const float*)d_in[6];
    const float* bn1_v  = (const float*)d_in[7];
    const float* bn2_g  = (const float*)d_in[8];
    const float* bn2_b  = (const float*)d_in[9];
    const float* bn2_m  = (const float*)d_in[10];
    const float* bn2_v  = (const float*)d_in[11];
    const float* bn3_g  = (const float*)d_in[12];
    const float* bn3_b  = (const float*)d_in[13];
    const float* bn3_m  = (const float*)d_in[14];
    const float* bn3_v  = (const float*)d_in[15];
    const float* W1     = (const float*)d_in[16];
    const float* att_s1 = (const float*)d_in[17];
    const float* att_d1 = (const float*)d_in[18];
    const float* b1     = (const float*)d_in[19];
    const float* W2     = (const float*)d_in[20];
    const float* att_s2 = (const float*)d_in[21];
    const float* att_d2 = (const float*)d_in[22];
    const float* b2     = (const float*)d_in[23];
    const float* cls_W  = (const float*)d_in[24];
    const float* cls_b  = (const float*)d_in[25];

    const int N = in_sizes[0] / 768;
    const int E = in_sizes[1] / 2;
    const int* srce = ei;
    const int* dste = ei + E;

    // workspace carve
    char* p = (char*)d_ws;
    auto carve = [&](size_t bytes) -> void* {
        void* r = (void*)p;
        p += (bytes + 255) & ~(size_t)255;
        return r;
    };
    bf16*  Wt0    = (bf16*) carve((size_t)64*768*2);
    bf16*  Wt1    = (bf16*) carve((size_t)64*64*2);
    bf16*  Wt2    = (bf16*) carve((size_t)64*64*2);
    bf16*  h0b    = (bf16*) carve((size_t)N*64*2);
    bf16*  h1b    = (bf16*) carve((size_t)N*64*2);
    bf16*  xwb    = (bf16*) carve((size_t)N*64*2);
    float* a_s    = (float*)carve((size_t)N*8*4);
    float* a_d    = (float*)carve((size_t)N*8*4);
    float* a_s2   = (float*)carve((size_t)N*4);
    float* a_d2   = (float*)carve((size_t)N*4);
    int*   cnt    = (int*)  carve((size_t)N*4);
    int*   rp     = (int*)  carve((size_t)(N+1)*4);
    int*   cursor = (int*)  carve((size_t)N*4);
    int*   bsum   = (int*)  carve(1024);
    u16*   in_src = (u16*)  carve((size_t)E*2);

    const int nb = (N + 255) / 256;
    const int PREP = 768*64 + 8192;

    k_prep<<<(PREP + N + 255)/256, 256, 0, stream>>>(proj_W, W1, W2, Wt0, Wt1, Wt2, cnt, N);

    // CSR (edges only; shared by both GAT layers)
    k_count<<<(E + 255)/256, 256, 0, stream>>>(dste, E, cnt);
    k_scan_block<<<nb, 256, 0, stream>>>(cnt, rp, bsum, N);
    k_finalize<<<nb, 256, 0, stream>>>(rp, bsum, cnt, cursor, N, nb);
    k_scatter<<<(E + 255)/256, 256, 0, stream>>>(srce, dste, E, cursor, in_src);

    // fused: h0 = elu(bn1(x @ W0 + b)); xw1 = h0 @ W1; H=8 logits
    k_fused_proj<<<(N + 63)/64, 256, 0, stream>>>(x, Wt0, Wt1, N,
            proj_b, bn1_g, bn1_b, bn1_m, bn1_v, att_s1, att_d1,
            h0b, xwb, a_s, a_d);

    // GAT layer 1 aggregation -> h1
    k_gat_agg<8, false><<<(N + 3)/4, 256, 0, stream>>>(xwb, a_s, a_d, rp, in_src,
            b1, bn2_g, bn2_b, bn2_m, bn2_v, h0b, h1b, nullptr, nullptr, nullptr, N);

    // layer 2 GEMM (MFMA) + H=1 logits
    k_gemm64<1, true, 1><<<(N + 63)/64, 256, 0, stream>>>(h1b, Wt2, N, 64,
            nullptr, nullptr, nullptr, nullptr, nullptr, xwb, a_s2, a_d2, att_s2, att_d2);

    // GAT layer 2 aggregation + classifier -> out
    k_gat_agg<1, true><<<(N + 3)/4, 256, 0, stream>>>(xwb, a_s2, a_d2, rp, in_src,
            b2, bn3_g, bn3_b, bn3_m, bn3_v, h1b, nullptr, (float*)d_out, cls_W, cls_b, N);
}

// Round 6
// 478.922 us; speedup vs baseline: 1.1022x; 1.1022x over previous
//
#include <hip/hip_runtime.h>

typedef __bf16 bf16;
typedef __attribute__((ext_vector_type(8))) __bf16 bf16x8;
typedef __attribute__((ext_vector_type(4))) __bf16 bf16x4;
typedef __attribute__((ext_vector_type(4))) float f32x4;
typedef unsigned short u16;

#define LSTR  40   // LDS row stride (bf16) for 32-wide K tiles -> 2-way bank alias (free)
#define LSTR2 72   // LDS row stride (bf16) for 64-wide tiles, 16B-aligned rows, 2-way alias
#define BN_EPS 1e-5f

__device__ inline float bfl(unsigned int w) { return __uint_as_float(w << 16); }
__device__ inline float bfh(unsigned int w) { return __uint_as_float(w & 0xffff0000u); }

// ---------------- prep: transpose fp32 weights -> bf16 transposed in ws; zero cnt -------
__global__ __launch_bounds__(256) void k_prep(
        const float* __restrict__ W0, const float* __restrict__ W1, const float* __restrict__ W2,
        bf16* __restrict__ Wt0, bf16* __restrict__ Wt1, bf16* __restrict__ Wt2,
        int* __restrict__ cnt, int n)
{
    int i = blockIdx.x*256 + threadIdx.x;
    const int T = 768*64 + 8192;
    if (i < 768*64)            { int k = i>>6, n_ = i&63;                  Wt0[n_*768+k] = (bf16)W0[i]; }
    else if (i < 768*64+4096)  { int j = i-768*64;      int k=j>>6,c=j&63; Wt1[c*64+k]  = (bf16)W1[j]; }
    else if (i < T)            { int j = i-768*64-4096; int k=j>>6,c=j&63; Wt2[c*64+k]  = (bf16)W2[j]; }
    int j = i - T;
    if (j >= 0 && j < n) cnt[j] = 0;      // self-loops handled inline in gat_agg
}

// ---------------- FUSED proj GEMM (K=768) + BN/ELU + layer-1 GEMM (K=64) + logits -------
__global__ __launch_bounds__(256) void k_fused_proj(
        const float* __restrict__ A, const bf16* __restrict__ Bt,   // x, Wt0[64][768]
        const bf16* __restrict__ W1t, int M,                        // Wt1[64][64] (n,k)
        const float* __restrict__ pb, const float* __restrict__ g,
        const float* __restrict__ bb, const float* __restrict__ mm, const float* __restrict__ vv,
        const float* __restrict__ att_s, const float* __restrict__ att_d,
        bf16* __restrict__ h0b, bf16* __restrict__ xwb,
        float* __restrict__ a_s, float* __restrict__ a_d)
{
    const int K = 768;
    __shared__ bf16 xs[2][64*LSTR];
    __shared__ bf16 bs[2][64*LSTR];
    __shared__ bf16 hs [64*LSTR2];
    __shared__ bf16 w1s[64*LSTR2];
    __shared__ float sC[64], cC[64];

    int t = threadIdx.x;
    int w = t >> 6, lane = t & 63;
    int q = lane >> 4, l16 = lane & 15;
    int row0 = blockIdx.x * 64;
    int sRow = t >> 2, sK = (t & 3) * 8;

    if (t < 64) {
        float s = rsqrtf(vv[t] + BN_EPS) * g[t];
        sC[t] = s;
        cC[t] = (pb[t] - mm[t]) * s + bb[t];
    }
    {
        int r = t >> 2, c0 = (t & 3) * 16;
        *(bf16x8*)(w1s + r*LSTR2 + c0)     = *(const bf16x8*)(W1t + r*64 + c0);
        *(bf16x8*)(w1s + r*LSTR2 + c0 + 8) = *(const bf16x8*)(W1t + r*64 + c0 + 8);
    }

    auto loadA = [&](int k0) -> bf16x8 {
        bf16x8 xv;
        #pragma unroll
        for (int i = 0; i < 8; ++i) xv[i] = (bf16)0.f;
        int gr = row0 + sRow;
        if (gr < M) {
            const float* ap = A + (size_t)gr*K + k0 + sK;
            float4 f0 = *(const float4*)ap;
            float4 f1 = *(const float4*)(ap + 4);
            xv[0]=(bf16)f0.x; xv[1]=(bf16)f0.y; xv[2]=(bf16)f0.z; xv[3]=(bf16)f0.w;
            xv[4]=(bf16)f1.x; xv[5]=(bf16)f1.y; xv[6]=(bf16)f1.z; xv[7]=(bf16)f1.w;
        }
        return xv;
    };
    auto loadB = [&](int k0) -> bf16x8 {
        return *(const bf16x8*)(Bt + (size_t)sRow*K + k0 + sK);
    };

    f32x4 acc[4];
    #pragma unroll
    for (int i = 0; i < 4; ++i) { acc[i][0]=0.f; acc[i][1]=0.f; acc[i][2]=0.f; acc[i][3]=0.f; }

    bf16x8 xv = loadA(0);
    bf16x8 bv = loadB(0);
    *(bf16x8*)(&xs[0][sRow*LSTR + sK]) = xv;
    *(bf16x8*)(&bs[0][sRow*LSTR + sK]) = bv;
    __syncthreads();

    int cur = 0;
    for (int k0 = 0; k0 < K; k0 += 32) {
        if (k0 + 32 < K) {                // prefetch next tile into registers
            xv = loadA(k0 + 32);
            bv = loadB(k0 + 32);
        }
        bf16x8 af = *(bf16x8*)(&xs[cur][(w*16 + l16)*LSTR + q*8]);
        #pragma unroll
        for (int tt = 0; tt < 4; ++tt) {
            bf16x8 bfr = *(bf16x8*)(&bs[cur][(tt*16 + l16)*LSTR + q*8]);
            acc[tt] = __builtin_amdgcn_mfma_f32_16x16x32_bf16(af, bfr, acc[tt], 0, 0, 0);
        }
        if (k0 + 32 < K) {                // write next tile to alternate buffer: 1 barrier/iter
            *(bf16x8*)(&xs[cur^1][sRow*LSTR + sK]) = xv;
            *(bf16x8*)(&bs[cur^1][sRow*LSTR + sK]) = bv;
            __syncthreads();
            cur ^= 1;
        }
    }

    // epilogue 1: h0 = ELU(BN(acc)) -> global h0b + LDS hs
    #pragma unroll
    for (int tt = 0; tt < 4; ++tt) {
        int col = tt*16 + l16;
        #pragma unroll
        for (int r = 0; r < 4; ++r) {
            int rl = w*16 + q*4 + r;
            float val = acc[tt][r] * sC[col] + cC[col];
            val = val > 0.f ? val : __expf(val) - 1.f;   // ELU
            hs[rl*LSTR2 + col] = (bf16)val;
            int row = row0 + rl;
            if (row < M) h0b[(size_t)row*64 + col] = (bf16)val;
        }
    }
    __syncthreads();

    // second GEMM: xw1 = h0_tile(64x64) @ W1 (K=64, 2 K-steps)
    f32x4 acc2[4];
    #pragma unroll
    for (int i = 0; i < 4; ++i) { acc2[i][0]=0.f; acc2[i][1]=0.f; acc2[i][2]=0.f; acc2[i][3]=0.f; }
    #pragma unroll
    for (int ks = 0; ks < 2; ++ks) {
        bf16x8 af = *(bf16x8*)(&hs[(w*16 + l16)*LSTR2 + ks*32 + q*8]);
        #pragma unroll
        for (int tt = 0; tt < 4; ++tt) {
            bf16x8 bfr = *(bf16x8*)(&w1s[(tt*16 + l16)*LSTR2 + ks*32 + q*8]);
            acc2[tt] = __builtin_amdgcn_mfma_f32_16x16x32_bf16(af, bfr, acc2[tt], 0, 0, 0);
        }
    }

    // epilogue 2: xwb (bf16) + fused H=8 attention logits from fp32 accumulator
    #pragma unroll
    for (int tt = 0; tt < 4; ++tt) {
        int col = tt*16 + l16;
        #pragma unroll
        for (int r = 0; r < 4; ++r) {
            int row = row0 + w*16 + q*4 + r;
            if (row < M) xwb[(size_t)row*64 + col] = (bf16)acc2[tt][r];
        }
    }
    #pragma unroll
    for (int r = 0; r < 4; ++r) {
        int row = row0 + w*16 + q*4 + r;
        float ps[4], pd[4];
        #pragma unroll
        for (int tt = 0; tt < 4; ++tt) {
            int col = tt*16 + l16;          // head = col>>3 = 2*tt + (l16>>3)
            ps[tt] = acc2[tt][r] * att_s[col];
            pd[tt] = acc2[tt][r] * att_d[col];
        }
        #pragma unroll
        for (int off = 1; off < 8; off <<= 1) {
            #pragma unroll
            for (int tt = 0; tt < 4; ++tt) {
                ps[tt] += __shfl_xor(ps[tt], off);
                pd[tt] += __shfl_xor(pd[tt], off);
            }
        }
        if ((l16 & 7) == 0 && row < M) {
            int hb = l16 >> 3;
            #pragma unroll
            for (int tt = 0; tt < 4; ++tt) {
                a_s[row*8 + 2*tt + hb] = ps[tt];
                a_d[row*8 + 2*tt + hb] = pd[tt];
            }
        }
    }
}

// ---------------- MFMA GEMM for layer 2 (K=64): raw xw + fused H=1 logits ---------------
template<int MODE, bool ABF, int H>
__global__ __launch_bounds__(256) void k_gemm64(
        const void* __restrict__ Av, const bf16* __restrict__ Bt, int M, int K,
        const float* __restrict__ pb, const float* __restrict__ g, const float* __restrict__ bb,
        const float* __restrict__ mm, const float* __restrict__ vv,
        bf16* __restrict__ outB,
        float* __restrict__ a_s, float* __restrict__ a_d,
        const float* __restrict__ att_s, const float* __restrict__ att_d)
{
    __shared__ bf16 xs[64*LSTR];
    __shared__ bf16 bs[64*LSTR];
    __shared__ float sC[64], cC[64];

    int t = threadIdx.x;
    int w = t >> 6, lane = t & 63;
    int q = lane >> 4, l16 = lane & 15;
    int row0 = blockIdx.x * 64;
    int sRow = t >> 2, sK = (t & 3) * 8;

    auto loadA = [&](int k0) -> bf16x8 {
        bf16x8 xv;
        #pragma unroll
        for (int i = 0; i < 8; ++i) xv[i] = (bf16)0.f;
        int gr = row0 + sRow;
        if (gr < M) {
            if constexpr (ABF) {
                xv = *(const bf16x8*)((const bf16*)Av + (size_t)gr*K + k0 + sK);
            } else {
                const float* ap = (const float*)Av + (size_t)gr*K + k0 + sK;
                float4 f0 = *(const float4*)ap;
                float4 f1 = *(const float4*)(ap + 4);
                xv[0]=(bf16)f0.x; xv[1]=(bf16)f0.y; xv[2]=(bf16)f0.z; xv[3]=(bf16)f0.w;
                xv[4]=(bf16)f1.x; xv[5]=(bf16)f1.y; xv[6]=(bf16)f1.z; xv[7]=(bf16)f1.w;
            }
        }
        return xv;
    };
    auto loadB = [&](int k0) -> bf16x8 {
        return *(const bf16x8*)(Bt + (size_t)sRow*K + k0 + sK);
    };

    f32x4 acc[4];
    #pragma unroll
    for (int i = 0; i < 4; ++i) { acc[i][0]=0.f; acc[i][1]=0.f; acc[i][2]=0.f; acc[i][3]=0.f; }

    bf16x8 xv = loadA(0);
    bf16x8 bv = loadB(0);

    for (int k0 = 0; k0 < K; k0 += 32) {
        *(bf16x8*)(xs + sRow*LSTR + sK) = xv;
        *(bf16x8*)(bs + sRow*LSTR + sK) = bv;
        __syncthreads();
        if (k0 + 32 < K) {
            xv = loadA(k0 + 32);
            bv = loadB(k0 + 32);
        }
        bf16x8 af = *(bf16x8*)(xs + (w*16 + l16)*LSTR + q*8);
        #pragma unroll
        for (int tt = 0; tt < 4; ++tt) {
            bf16x8 bfr = *(bf16x8*)(bs + (tt*16 + l16)*LSTR + q*8);
            acc[tt] = __builtin_amdgcn_mfma_f32_16x16x32_bf16(af, bfr, acc[tt], 0, 0, 0);
        }
        __syncthreads();
    }

    if constexpr (MODE == 0) {
        if (t < 64) {
            float s = rsqrtf(vv[t] + BN_EPS) * g[t];
            sC[t] = s;
            cC[t] = (pb[t] - mm[t]) * s + bb[t];
        }
        __syncthreads();
    }

    #pragma unroll
    for (int tt = 0; tt < 4; ++tt) {
        int col = tt*16 + l16;
        #pragma unroll
        for (int r = 0; r < 4; ++r) {
            int row = row0 + w*16 + q*4 + r;
            if (row < M) {
                float val = acc[tt][r];
                if constexpr (MODE == 0) {
                    val = val * sC[col] + cC[col];
                    val = val > 0.f ? val : __expf(val) - 1.f;
                }
                outB[(size_t)row*64 + col] = (bf16)val;
            }
        }
    }

    if constexpr (MODE == 1) {
        #pragma unroll
        for (int r = 0; r < 4; ++r) {
            int row = row0 + w*16 + q*4 + r;
            if constexpr (H == 1) {
                float ps = 0.f, pd = 0.f;
                #pragma unroll
                for (int tt = 0; tt < 4; ++tt) {
                    int col = tt*16 + l16;
                    ps += acc[tt][r] * att_s[col];
                    pd += acc[tt][r] * att_d[col];
                }
                #pragma unroll
                for (int off = 1; off < 16; off <<= 1) {
                    ps += __shfl_xor(ps, off);
                    pd += __shfl_xor(pd, off);
                }
                if (l16 == 0 && row < M) { a_s[row] = ps; a_d[row] = pd; }
            } else {
                float ps[4], pd[4];
                #pragma unroll
                for (int tt = 0; tt < 4; ++tt) {
                    int col = tt*16 + l16;
                    ps[tt] = acc[tt][r] * att_s[col];
                    pd[tt] = acc[tt][r] * att_d[col];
                }
                #pragma unroll
                for (int off = 1; off < 8; off <<= 1) {
                    #pragma unroll
                    for (int tt = 0; tt < 4; ++tt) {
                        ps[tt] += __shfl_xor(ps[tt], off);
                        pd[tt] += __shfl_xor(pd[tt], off);
                    }
                }
                if ((l16 & 7) == 0 && row < M) {
                    int hb = l16 >> 3;
                    #pragma unroll
                    for (int tt = 0; tt < 4; ++tt) {
                        a_s[row*8 + 2*tt + hb] = ps[tt];
                        a_d[row*8 + 2*tt + hb] = pd[tt];
                    }
                }
            }
        }
    }
}

// ---------------- CSR build (edges only; self-loops inline in gat_agg) ----------------
__global__ __launch_bounds__(256) void k_count(const int* __restrict__ dst, int E, int* cnt) {
    int i = blockIdx.x*256 + threadIdx.x;
    if (i < E) atomicAdd(&cnt[dst[i]], 1);
}
__global__ __launch_bounds__(256) void k_scan_block(const int* __restrict__ cnt,
        int* __restrict__ rp, int* __restrict__ bsum, int n) {
    __shared__ int s[256];
    int t = threadIdx.x, v = blockIdx.x*256 + t;
    int x = (v < n) ? cnt[v] : 0;
    s[t] = x; __syncthreads();
    for (int off = 1; off < 256; off <<= 1) {
        int y = (t >= off) ? s[t-off] : 0;
        __syncthreads();
        s[t] += y;
        __syncthreads();
    }
    if (v < n) rp[v+1] = s[t];
    if (t == 255) bsum[blockIdx.x] = s[255];
}
// finalize with fused bsum scan (nb <= 256; N=50000 -> nb=196)
__global__ __launch_bounds__(256) void k_finalize(int* __restrict__ rp, const int* __restrict__ bsum,
        const int* __restrict__ cnt, int* __restrict__ cursor, int n, int nb) {
    __shared__ int s[256];
    int t = threadIdx.x;
    int x = (t < nb) ? bsum[t] : 0;
    s[t] = x; __syncthreads();
    for (int off = 1; off < 256; off <<= 1) {
        int y = (t >= off) ? s[t-off] : 0;
        __syncthreads();
        s[t] += y;
        __syncthreads();
    }
    int v = blockIdx.x*256 + t;
    if (v < n) {
        int b = v >> 8;
        int off0 = (b == 0) ? 0 : s[b-1];
        int val = rp[v+1] + off0;
        rp[v+1] = val;
        cursor[v] = val - cnt[v];          // = rp[v]
        if (v == 0) rp[0] = 0;
    }
}
__global__ __launch_bounds__(256) void k_scatter(const int* __restrict__ src, const int* __restrict__ dst,
        int E, int* __restrict__ cursor, u16* __restrict__ in_src) {
    int i = blockIdx.x*256 + threadIdx.x;
    if (i < E) {
        int pos = atomicAdd(&cursor[dst[i]], 1);
        in_src[pos] = (u16)src[i];         // N < 65536
    }
}

// ---------------- GAT aggregation, 4-edges-per-wave, 16-edge-deep main loop -------------
// lane = eg*16 + s (eg 0..3, s 0..15): edge-group eg handles edges e+eg, e+4+eg, e+8+eg,
// e+12+eg; lane s owns channels 4s..4s+3 via one 8B uint2 load. Main loop issues 4 index
// loads + 4 a_src + 4 xw gathers together (8 loads in flight) -> half the serial latency
// rounds of the 8-deep version. Butterfly over eg bits {16,32} merges partials.
template<int H, bool CLS>
__global__ __launch_bounds__(256) void k_gat_agg(const bf16* __restrict__ xwb,
        const float* __restrict__ a_src, const float* __restrict__ a_dst,
        const int* __restrict__ rp, const u16* __restrict__ in_src,
        const float* __restrict__ bias,
        const float* __restrict__ g_, const float* __restrict__ bb,
        const float* __restrict__ mm, const float* __restrict__ vv,
        const bf16* __restrict__ resid, bf16* __restrict__ outB, float* __restrict__ outF,
        const float* __restrict__ clsW, const float* __restrict__ clsb, int n)
{
    int wv = (blockIdx.x*256 + threadIdx.x) >> 6;
    int lane = threadIdx.x & 63;
    if (wv >= n) return;
    int eg = lane >> 4;          // edge group 0..3
    int s  = lane & 15;          // channel group
    int c0 = s * 4;
    int h  = (H == 8) ? (s >> 1) : 0;
    float adst = a_dst[(size_t)wv*H + h];

    float a0 = 0.f, a1 = 0.f, a2 = 0.f, a3 = 0.f, den = 0.f;

    // self-loop term: only edge-group 0 contributes (avoids 4x counting after butterfly)
    if (eg == 0) {
        float asf = a_src[(size_t)wv*H + h] + adst;
        asf = (asf > 0.f) ? asf : 0.2f*asf;
        float ex = __expf(asf);
        uint2 xw = *(const uint2*)(xwb + (size_t)wv*64 + c0);
        a0 = ex*bfl(xw.x); a1 = ex*bfh(xw.x); a2 = ex*bfl(xw.y); a3 = ex*bfh(xw.y);
        den = ex;
    }

    int beg = rp[wv], end = rp[wv+1];
    int e = beg;
    for (; e + 16 <= end; e += 16) {         // 16 edges/iter: 4 gather-pairs in flight
        int u0 = (int)in_src[e + eg];
        int u1 = (int)in_src[e + 4 + eg];
        int u2 = (int)in_src[e + 8 + eg];
        int u3 = (int)in_src[e + 12 + eg];
        float s0 = a_src[(size_t)u0*H + h];
        float s1 = a_src[(size_t)u1*H + h];
        float s2 = a_src[(size_t)u2*H + h];
        float s3 = a_src[(size_t)u3*H + h];
        uint2 x0 = *(const uint2*)(xwb + (size_t)u0*64 + c0);
        uint2 x1 = *(const uint2*)(xwb + (size_t)u1*64 + c0);
        uint2 x2 = *(const uint2*)(xwb + (size_t)u2*64 + c0);
        uint2 x3 = *(const uint2*)(xwb + (size_t)u3*64 + c0);
        float al0 = s0 + adst; al0 = (al0 > 0.f) ? al0 : 0.2f*al0;
        float al1 = s1 + adst; al1 = (al1 > 0.f) ? al1 : 0.2f*al1;
        float al2 = s2 + adst; al2 = (al2 > 0.f) ? al2 : 0.2f*al2;
        float al3 = s3 + adst; al3 = (al3 > 0.f) ? al3 : 0.2f*al3;
        float e0 = __expf(al0), e1 = __expf(al1), e2 = __expf(al2), e3 = __expf(al3);
        a0 += e0*bfl(x0.x) + e1*bfl(x1.x) + e2*bfl(x2.x) + e3*bfl(x3.x);
        a1 += e0*bfh(x0.x) + e1*bfh(x1.x) + e2*bfh(x2.x) + e3*bfh(x3.x);
        a2 += e0*bfl(x0.y) + e1*bfl(x1.y) + e2*bfl(x2.y) + e3*bfl(x3.y);
        a3 += e0*bfh(x0.y) + e1*bfh(x1.y) + e2*bfh(x2.y) + e3*bfh(x3.y);
        den += e0 + e1 + e2 + e3;
    }
    for (; e + 8 <= end; e += 8) {           // 8 edges/iter
        int u0 = (int)in_src[e + eg];
        int u1 = (int)in_src[e + 4 + eg];
        float s0 = a_src[(size_t)u0*H + h];
        float s1 = a_src[(size_t)u1*H + h];
        uint2 x0 = *(const uint2*)(xwb + (size_t)u0*64 + c0);
        uint2 x1 = *(const uint2*)(xwb + (size_t)u1*64 + c0);
        float al0 = s0 + adst; al0 = (al0 > 0.f) ? al0 : 0.2f*al0;
        float al1 = s1 + adst; al1 = (al1 > 0.f) ? al1 : 0.2f*al1;
        float e0 = __expf(al0), e1 = __expf(al1);
        a0 += e0*bfl(x0.x) + e1*bfl(x1.x);
        a1 += e0*bfh(x0.x) + e1*bfh(x1.x);
        a2 += e0*bfl(x0.y) + e1*bfl(x1.y);
        a3 += e0*bfh(x0.y) + e1*bfh(x1.y);
        den += e0 + e1;
    }
    for (; e < end; e += 4) {                // masked tail, 4 at a time
        int idx = e + eg;
        bool act = idx < end;
        int u = act ? (int)in_src[idx] : 0;
        float sv = a_src[(size_t)u*H + h];
        uint2 xw = *(const uint2*)(xwb + (size_t)u*64 + c0);
        float al = sv + adst; al = (al > 0.f) ? al : 0.2f*al;
        float ex = act ? __expf(al) : 0.f;
        a0 += ex*bfl(xw.x); a1 += ex*bfh(xw.x); a2 += ex*bfl(xw.y); a3 += ex*bfh(xw.y);
        den += ex;
    }

    // merge the 4 edge-group partials (lanes xor 16, 32)
    #pragma unroll
    for (int off = 16; off < 64; off <<= 1) {
        a0 += __shfl_xor(a0, off);
        a1 += __shfl_xor(a1, off);
        a2 += __shfl_xor(a2, off);
        a3 += __shfl_xor(a3, off);
        den += __shfl_xor(den, off);
    }

    float inv = 1.f / den;
    uint2 rz = *(const uint2*)(resid + (size_t)wv*64 + c0);
    float v[4]  = { a0*inv, a1*inv, a2*inv, a3*inv };
    float rv[4] = { bfl(rz.x), bfh(rz.x), bfl(rz.y), bfh(rz.y) };
    #pragma unroll
    for (int j = 0; j < 4; ++j) {
        int c = c0 + j;
        float val = v[j] + bias[c];
        float sc = rsqrtf(vv[c] + BN_EPS) * g_[c];
        val = (val - mm[c]) * sc + bb[c];
        val += rv[j];
        val = (val > 0.f) ? val : __expf(val) - 1.f;   // ELU
        v[j] = val;
    }

    if constexpr (!CLS) {
        if (eg == 0) {
            bf16x4 o;
            o[0] = (bf16)v[0]; o[1] = (bf16)v[1]; o[2] = (bf16)v[2]; o[3] = (bf16)v[3];
            *(bf16x4*)(outB + (size_t)wv*64 + c0) = o;
        }
    } else {
        // classifier: v[] duplicated across eg groups, so butterfly ONLY over the s-bits
        // {1,2,4,8} -> each 16-lane group ends with the full 64-channel dot (4 levels, 32 shfl).
        float p[8];
        #pragma unroll
        for (int o = 0; o < 8; ++o) {
            p[o] = v[0]*clsW[(c0+0)*8+o] + v[1]*clsW[(c0+1)*8+o]
                 + v[2]*clsW[(c0+2)*8+o] + v[3]*clsW[(c0+3)*8+o];
        }
        #pragma unroll
        for (int off = 1; off < 16; off <<= 1) {
            #pragma unroll
            for (int o = 0; o < 8; ++o) p[o] += __shfl_xor(p[o], off);
        }
        if (lane < 8) outF[(size_t)wv*8 + lane] = p[lane] + clsb[lane];
    }
}

// ---------------- host ----------------
extern "C" void kernel_launch(void* const* d_in, const int* in_sizes, int n_in,
                              void* d_out, int out_size, void* d_ws, size_t ws_size,
                              hipStream_t stream)
{
    const float* x      = (const float*)d_in[0];
    const int*   ei     = (const int*)  d_in[1];
    const float* proj_W = (const float*)d_in[2];
    const float* proj_b = (const float*)d_in[3];
    const float* bn1_g  = (const float*)d_in[4];
    const float* bn1_b  = (const float*)d_in[5];
    const float* bn1_m  = (const float*)d_in[6];
    const float* bn1_v  = (const float*)d_in[7];
    const float* bn2_g  = (const float*)d_in[8];
    const float* bn2_b  = (const float*)d_in[9];
    const float* bn2_m  = (const float*)d_in[10];
    const float* bn2_v  = (const float*)d_in[11];
    const float* bn3_g  = (const float*)d_in[12];
    const float* bn3_b  = (const float*)d_in[13];
    const float* bn3_m  = (const float*)d_in[14];
    const float* bn3_v  = (const float*)d_in[15];
    const float* W1     = (const float*)d_in[16];
    const float* att_s1 = (const float*)d_in[17];
    const float* att_d1 = (const float*)d_in[18];
    const float* b1     = (const float*)d_in[19];
    const float* W2     = (const float*)d_in[20];
    const float* att_s2 = (const float*)d_in[21];
    const float* att_d2 = (const float*)d_in[22];
    const float* b2     = (const float*)d_in[23];
    const float* cls_W  = (const float*)d_in[24];
    const float* cls_b  = (const float*)d_in[25];

    const int N = in_sizes[0] / 768;
    const int E = in_sizes[1] / 2;
    const int* srce = ei;
    const int* dste = ei + E;

    // workspace carve
    char* p = (char*)d_ws;
    auto carve = [&](size_t bytes) -> void* {
        void* r = (void*)p;
        p += (bytes + 255) & ~(size_t)255;
        return r;
    };
    bf16*  Wt0    = (bf16*) carve((size_t)64*768*2);
    bf16*  Wt1    = (bf16*) carve((size_t)64*64*2);
    bf16*  Wt2    = (bf16*) carve((size_t)64*64*2);
    bf16*  h0b    = (bf16*) carve((size_t)N*64*2);
    bf16*  h1b    = (bf16*) carve((size_t)N*64*2);
    bf16*  xwb    = (bf16*) carve((size_t)N*64*2);
    float* a_s    = (float*)carve((size_t)N*8*4);
    float* a_d    = (float*)carve((size_t)N*8*4);
    float* a_s2   = (float*)carve((size_t)N*4);
    float* a_d2   = (float*)carve((size_t)N*4);
    int*   cnt    = (int*)  carve((size_t)N*4);
    int*   rp     = (int*)  carve((size_t)(N+1)*4);
    int*   cursor = (int*)  carve((size_t)N*4);
    int*   bsum   = (int*)  carve(1024);
    u16*   in_src = (u16*)  carve((size_t)E*2);

    const int nb = (N + 255) / 256;
    const int PREP = 768*64 + 8192;

    k_prep<<<(PREP + N + 255)/256, 256, 0, stream>>>(proj_W, W1, W2, Wt0, Wt1, Wt2, cnt, N);

    // CSR (edges only; shared by both GAT layers)
    k_count<<<(E + 255)/256, 256, 0, stream>>>(dste, E, cnt);
    k_scan_block<<<nb, 256, 0, stream>>>(cnt, rp, bsum, N);
    k_finalize<<<nb, 256, 0, stream>>>(rp, bsum, cnt, cursor, N, nb);
    k_scatter<<<(E + 255)/256, 256, 0, stream>>>(srce, dste, E, cursor, in_src);

    // fused: h0 = elu(bn1(x @ W0 + b)); xw1 = h0 @ W1; H=8 logits
    k_fused_proj<<<(N + 63)/64, 256, 0, stream>>>(x, Wt0, Wt1, N,
            proj_b, bn1_g, bn1_b, bn1_m, bn1_v, att_s1, att_d1,
            h0b, xwb, a_s, a_d);

    // GAT layer 1 aggregation -> h1
    k_gat_agg<8, false><<<(N + 3)/4, 256, 0, stream>>>(xwb, a_s, a_d, rp, in_src,
            b1, bn2_g, bn2_b, bn2_m, bn2_v, h0b, h1b, nullptr, nullptr, nullptr, N);

    // layer 2 GEMM (MFMA) + H=1 logits
    k_gemm64<1, true, 1><<<(N + 63)/64, 256, 0, stream>>>(h1b, Wt2, N, 64,
            nullptr, nullptr, nullptr, nullptr, nullptr, xwb, a_s2, a_d2, att_s2, att_d2);

    // GAT layer 2 aggregation + classifier -> out
    k_gat_agg<1, true><<<(N + 3)/4, 256, 0, stream>>>(xwb, a_s2, a_d2, rp, in_src,
            b2, bn3_g, bn3_b, bn3_m, bn3_v, h1b, nullptr, (float*)d_out, cls_W, cls_b, N);
}